// Round 5
// baseline (680.849 us; speedup 1.0000x reference)
//
#include <hip/hip_runtime.h>
#include <hip/hip_fp16.h>

#define CCH 16

// ======================= zero helper =======================
__global__ void zero_f4k(float4* __restrict__ p, int n4) {
    int i = blockIdx.x * blockDim.x + threadIdx.x;
    if (i < n4) p[i] = make_float4(0.f, 0.f, 0.f, 0.f);
}

__global__ void zero_f(float* __restrict__ p, int n) {
    int i = blockIdx.x * blockDim.x + threadIdx.x;
    if (i < n) p[i] = 0.0f;
}

// ======================= K-replicated packed-f16 atomic path =======================
// 8 threads per point (one float2 / half2 channel-pair each). Replica chosen by
// point index -> ops-per-line at the coherence point drops from 128 to 128/K.
template <int K>
__global__ void scatter_add_h2_rep(const float2* __restrict__ in2,
                                   const int* __restrict__ seg,
                                   __half2* __restrict__ sums,   // [K][M*8]
                                   float* __restrict__ counts,   // [K][M]
                                   int N, int M8, int M) {
    int tid = blockIdx.x * blockDim.x + threadIdx.x;   // 8*N threads
    int p = tid >> 3;
    int cp = tid & 7;
    if (p >= N) return;
    int r = p & (K - 1);
    int s = seg[p];
    float2 v = in2[tid];
    __half2 h = __floats2half2_rn(v.x, v.y);
    unsafeAtomicAdd(&sums[(size_t)r * M8 + (size_t)s * 8 + cp], h);
    if (cp == 0) unsafeAtomicAdd(&counts[(size_t)r * M + s], 1.0f);
}

// reduce replicas + divide by clamped count; thread per (segment, channel-pair)
template <int K>
__global__ void reduce_mean(const __half2* __restrict__ sums,
                            const float* __restrict__ counts,
                            float2* __restrict__ out, int M8, int M) {
    int i = blockIdx.x * blockDim.x + threadIdx.x;
    if (i >= M8) return;
    int s = i >> 3;
    float ax = 0.f, ay = 0.f, cnt = 0.f;
#pragma unroll
    for (int r = 0; r < K; ++r) {
        float2 v = __half22float2(sums[(size_t)r * M8 + i]);
        ax += v.x; ay += v.y;
        cnt += counts[(size_t)r * M + s];
    }
    float inv = 1.0f / fmaxf(cnt, 1.0f);
    out[i] = make_float2(ax * inv, ay * inv);
}

// ======================= fallback (round-1 fp32 atomic) path =======================
__global__ void scatter_add_kernel(const float* __restrict__ in,
                                   const int* __restrict__ seg,
                                   float* __restrict__ sums,
                                   float* __restrict__ counts,
                                   int N) {
    int tid = blockIdx.x * blockDim.x + threadIdx.x;
    int p = tid >> 4;
    int c = tid & 15;
    if (p >= N) return;
    int s = seg[p];
    unsafeAtomicAdd(&sums[s * CCH + c], in[tid]);
    if (c == 0) unsafeAtomicAdd(&counts[s], 1.0f);
}

__global__ void finalize_kernel(float4* __restrict__ out,
                                const float* __restrict__ counts,
                                int n4) {
    int i = blockIdx.x * blockDim.x + threadIdx.x;
    if (i >= n4) return;
    int m = i >> 2;
    float inv = 1.0f / fmaxf(counts[m], 1.0f);
    float4 v = out[i];
    v.x *= inv; v.y *= inv; v.z *= inv; v.w *= inv;
    out[i] = v;
}

// ======================= launch =======================
template <int K>
static void run_rep(const float* in, const int* seg, float* out,
                    void* d_ws, int N, int M, hipStream_t stream) {
    const int M8 = M * 8;
    __half2* sums = (__half2*)d_ws;                                  // K * M8 half2
    float* counts = (float*)((char*)d_ws + (size_t)K * M8 * 4);      // K * M floats

    // zero sums+counts: contiguous K*M*36 bytes
    size_t bytes = (size_t)K * M * 36;
    int n4 = (int)(bytes / 16);
    zero_f4k<<<(n4 + 255) / 256, 256, 0, stream>>>((float4*)d_ws, n4);

    long long total = (long long)N * 8;
    scatter_add_h2_rep<K><<<(int)((total + 255) / 256), 256, 0, stream>>>(
        (const float2*)in, seg, sums, counts, N, M8, M);

    reduce_mean<K><<<(M8 + 255) / 256, 256, 0, stream>>>(
        sums, counts, (float2*)out, M8, M);
}

extern "C" void kernel_launch(void* const* d_in, const int* in_sizes, int n_in,
                              void* d_out, int out_size, void* d_ws, size_t ws_size,
                              hipStream_t stream) {
    const float* in  = (const float*)d_in[0];
    const int*   seg = (const int*)d_in[1];
    float* out = (float*)d_out;

    const int N = in_sizes[0] / CCH;  // 4,000,000 points
    const int M = out_size / CCH;     // 500,000 segments

    const size_t per_rep = (size_t)M * 36;  // 16 MB sums + 2 MB counts per replica

    if (ws_size >= 4 * per_rep) {
        run_rep<4>(in, seg, out, d_ws, N, M, stream);
    } else if (ws_size >= 2 * per_rep) {
        run_rep<2>(in, seg, out, d_ws, N, M, stream);
    } else if (ws_size >= per_rep) {
        run_rep<1>(in, seg, out, d_ws, N, M, stream);
    } else {
        // fp32 atomic path directly into d_out (needs only counts[M] in ws)
        float* counts = (float*)d_ws;
        int n4 = out_size / 4;
        zero_f4k<<<(n4 + 255) / 256, 256, 0, stream>>>((float4*)d_out, n4);
        zero_f<<<(M + 255) / 256, 256, 0, stream>>>(counts, M);
        long long total = (long long)N * CCH;
        scatter_add_kernel<<<(int)((total + 255) / 256), 256, 0, stream>>>(
            in, seg, out, counts, N);
        finalize_kernel<<<(n4 + 255) / 256, 256, 0, stream>>>(
            (float4*)d_out, counts, n4);
    }
}